// Round 12
// baseline (224.903 us; speedup 1.0000x reference)
//
#include <hip/hip_runtime.h>

#define DEVINL __device__ __forceinline__

typedef _Float16 h4 __attribute__((ext_vector_type(4)));
typedef _Float16 h8 __attribute__((ext_vector_type(8)));
typedef float    f4 __attribute__((ext_vector_type(4)));

DEVINL float fexp2(float x){ return __builtin_amdgcn_exp2f(x); }
DEVINL float frcp (float x){ return __builtin_amdgcn_rcpf(x); }

#define LOG2E 1.4426950408889634f

// ---------------------------------------------------------------------------
// Kernel 1: table [dir][idx][row 0..15] f16x4 { -l2e*gr, -l2e*gz, 2l2e*gn, 0 }
// rows >= H zero. gr/gz include BOTH biases; gn only bih_n (bhh_n goes to the
// n-MFMA C operand). Plus the static part of out[b].
// ---------------------------------------------------------------------------
template<int H>
DEVINL void pre_entry16(int t, const float* __restrict__ emb,
    const float* __restrict__ Wih_f, const float* __restrict__ bih_f, const float* __restrict__ bhh_f,
    const float* __restrict__ Wih_b, const float* __restrict__ bih_b, const float* __restrict__ bhh_b,
    h4* __restrict__ G, int N)
{
  constexpr int E = H - 1;
  const int dir = t / (N * 16);
  const int rem = t - dir * (N * 16);
  const int idx = rem >> 4;
  const int row = rem & 15;
  h4 g; g[0]=(_Float16)0.f; g[1]=(_Float16)0.f; g[2]=(_Float16)0.f; g[3]=(_Float16)0.f;
  if (row < H){
    const float* Wih = dir ? Wih_b : Wih_f;
    const float* bih = dir ? bih_b : bih_f;
    const float* bhh = dir ? bhh_b : bhh_f;
    const float* e = emb + (size_t)idx * E;
    float gr = bih[row]       + bhh[row];
    float gz = bih[H + row]   + bhh[H + row];
    float gn = bih[2*H + row];
#pragma unroll
    for (int q2 = 0; q2 < E; q2++){
      const float ev = e[q2];
      gr = fmaf(Wih[( row      )*H + q2], ev, gr);
      gz = fmaf(Wih[( H + row  )*H + q2], ev, gz);
      gn = fmaf(Wih[(2*H + row )*H + q2], ev, gn);
    }
    g[0] = (_Float16)(-LOG2E * gr);
    g[1] = (_Float16)(-LOG2E * gz);
    g[2] = (_Float16)(2.f * LOG2E * gn);
  }
  G[t] = g;
}

__global__ __launch_bounds__(256) void pre_kernel(
    const float* __restrict__ emb_dp, const float* __restrict__ emb_cp,
    const float* __restrict__ Wih_dpf, const float* __restrict__ bih_dpf, const float* __restrict__ bhh_dpf,
    const float* __restrict__ Wih_dpb, const float* __restrict__ bih_dpb, const float* __restrict__ bhh_dpb,
    const float* __restrict__ Wih_cpf, const float* __restrict__ bih_cpf, const float* __restrict__ bhh_cpf,
    const float* __restrict__ Wih_cpb, const float* __restrict__ bih_cpb, const float* __restrict__ bhh_cpb,
    const float* __restrict__ stat, const float* __restrict__ fc_all_w, const float* __restrict__ fc_all_b,
    const float* __restrict__ fc_dp_b, const float* __restrict__ fc_cp_b,
    h4* __restrict__ Gdp, h4* __restrict__ Gcp, float* __restrict__ out)
{
  constexpr int NDP_E = 2 * 4096 * 16;    // 131072
  constexpr int NCP_E = 2 * 10000 * 16;   // 320000
  const int t = blockIdx.x * 256 + threadIdx.x;
  if (t < NDP_E){
    pre_entry16<9>(t, emb_dp, Wih_dpf, bih_dpf, bhh_dpf, Wih_dpb, bih_dpb, bhh_dpb, Gdp, 4096);
  } else if (t < NDP_E + NCP_E){
    pre_entry16<11>(t - NDP_E, emb_cp, Wih_cpf, bih_cpf, bhh_cpf, Wih_cpb, bih_cpb, bhh_cpb, Gcp, 10000);
  } else if (t < NDP_E + NCP_E + 4096){
    const int b = t - (NDP_E + NCP_E);
    float s = fc_all_b[0] + fc_all_w[20]*fc_dp_b[0] + fc_all_w[21]*fc_cp_b[0];
    const float* st = stat + (size_t)b * 20;
#pragma unroll
    for (int k = 0; k < 20; k++) s = fmaf(fc_all_w[k], st[k], s);
    out[b] = s;
  }
}

// ---------------------------------------------------------------------------
// Kernel 2: MFMA-batched GRU. One wave = 16 same-direction sequences.
// v_mfma_f32_16x16x16_f16, A = U weights (rows=gate elements, k=h dims, col H
// = dt weight), B = h (k=h dims + dt at k=H, cols = sequences), C = table g.
// D rows per lane == next step's B k-indices per lane -> recurrence is
// LANE-LOCAL between steps. No LDS, no cross-lane ops in the loop.
// ---------------------------------------------------------------------------
template<int H, int N>
DEVINL void gru_mfma(int gwid, int dir,
    const int* __restrict__ seq, const float* __restrict__ tim,
    const h4* __restrict__ Gtab,
    const float* __restrict__ Wih, const float* __restrict__ Whh, const float* __restrict__ bhh,
    const float* __restrict__ fc_w, float wt, float* __restrict__ out)
{
  constexpr int S = 512;
  const int lane = threadIdx.x & 63;
  const int c = lane & 15;          // sequence column
  const int q = lane >> 4;          // k/row block
  const int b = gwid * 16 + c;      // batch row

  // A fragments: lane supplies A[row=c][k=4q+j]; rows >= H zeroed (guarded).
  h4 Ar, Az, An;
#pragma unroll
  for (int j = 0; j < 4; j++){
    const int k = 4*q + j;
    float ar = 0.f, az = 0.f, an = 0.f;
    if (c < H){
      if (k < H){
        ar = -LOG2E      * Whh[( c      )*H + k];
        az = -LOG2E      * Whh[( H + c  )*H + k];
        an = 2.f * LOG2E * Whh[(2*H + c )*H + k];
      } else if (k == H){
        ar = -LOG2E * Wih[( c     )*H + (H-1)];   // dt weight (r)
        az = -LOG2E * Wih[( H + c )*H + (H-1)];   // dt weight (z)
        an = 0.f;                                  // dt of n handled on VALU
      }
    }
    Ar[j] = (_Float16)ar; Az[j] = (_Float16)az; An[j] = (_Float16)an;
  }

  // Per-D-row constants (i = 4q+reg): n-gate recurrent bias (C operand),
  // n-gate dt weight, fc weight.
  f4 Cn; float Wnd[4], fcw[4];
#pragma unroll
  for (int reg = 0; reg < 4; reg++){
    const int i = 4*q + reg;
    Cn[reg]  = (i < H) ? 2.f * LOG2E * bhh[2*H + i] : 0.f;
    Wnd[reg] = (i < H) ? 2.f * LOG2E * Wih[(2*H + i)*H + (H-1)] : 0.f;
    fcw[reg] = (i < H) ? fc_w[dir*H + i] : 0.f;
  }

  const int*   sp = seq + (size_t)b * S;
  const float* tp = tim + (size_t)b * S;
  // table: [dir][idx][16 rows x 8B]; this lane reads rows 4q..4q+3 (32B)
  const char* gB = (const char*)Gtab + ((size_t)dir * N) * 128 + q * 32;

  float hm[4] = {0.f, 0.f, 0.f, 0.f};   // f32 master of D rows 4q..4q+3
  float prev = 0.f;

  int ic[4]; float tc[4];
  int icn[4] = {0,0,0,0}; float tcn[4] = {0,0,0,0};
  {
    const int p0 = dir ? (S - 4) : 0;
    int4   iv = *reinterpret_cast<const int4*  >(sp + p0);
    float4 tv = *reinterpret_cast<const float4*>(tp + p0);
    if (dir){ ic[0]=iv.w; ic[1]=iv.z; ic[2]=iv.y; ic[3]=iv.x;
              tc[0]=tv.w; tc[1]=tv.z; tc[2]=tv.y; tc[3]=tv.x; }
    else    { ic[0]=iv.x; ic[1]=iv.y; ic[2]=iv.z; ic[3]=iv.w;
              tc[0]=tv.x; tc[1]=tv.y; tc[2]=tv.z; tc[3]=tv.w; }
  }

  // depth-2 table-gather ring (two 16B loads per step: rows 4q..4q+1, 4q+2..4q+3)
  h8 GbL[4], GbH[4];
  GbL[0] = *(const h8*)(gB + (unsigned)ic[0] * 128u);
  GbH[0] = *(const h8*)(gB + (unsigned)ic[0] * 128u + 16);
  GbL[1] = *(const h8*)(gB + (unsigned)ic[1] * 128u);
  GbH[1] = *(const h8*)(gB + (unsigned)ic[1] * 128u + 16);

#pragma unroll 1
  for (int ch = 0; ch < S/4; ++ch){
    if (ch < S/4 - 1){
      const int p0 = dir ? (S - 8 - 4*ch) : (4*ch + 4);
      int4   iv = *reinterpret_cast<const int4*  >(sp + p0);
      float4 tv = *reinterpret_cast<const float4*>(tp + p0);
      if (dir){ icn[0]=iv.w; icn[1]=iv.z; icn[2]=iv.y; icn[3]=iv.x;
                tcn[0]=tv.w; tcn[1]=tv.z; tcn[2]=tv.y; tcn[3]=tv.x; }
      else    { icn[0]=iv.x; icn[1]=iv.y; icn[2]=iv.z; icn[3]=iv.w;
                tcn[0]=tv.x; tcn[1]=tv.y; tcn[2]=tv.z; tcn[3]=tv.w; }
    }
#pragma unroll
    for (int k = 0; k < 4; k++){
      // prefetch step ch*4+k+2 (stale icn on last chunk: valid idx, unused)
      {
        const int pidx = (k==0) ? ic[2] : (k==1) ? ic[3] : (k==2) ? icn[0] : icn[1];
        GbL[(k+2)&3] = *(const h8*)(gB + (unsigned)pidx * 128u);
        GbH[(k+2)&3] = *(const h8*)(gB + (unsigned)pidx * 128u + 16);
      }

      const float tcur = tc[k];
      const float dtv = fmaxf(tcur - prev, 0.f); prev = tcur;

      // B fragment: h (f16) at k=4q+j; dt at k==H (lane block q==H>>2, j==H&3)
      h4 bf;
      bf[0] = (_Float16)hm[0]; bf[1] = (_Float16)hm[1];
      bf[2] = (_Float16)hm[2]; bf[3] = (_Float16)hm[3];
      if (q == (H >> 2)) bf[H & 3] = (_Float16)dtv;

      // C operands from the table (rows 4q..4q+3 of idx)
      const h8 lo = GbL[k], hi = GbH[k];
      f4 Cr, Cz; float gn4[4];
      Cr[0]=(float)lo[0]; Cz[0]=(float)lo[1]; gn4[0]=(float)lo[2];
      Cr[1]=(float)lo[4]; Cz[1]=(float)lo[5]; gn4[1]=(float)lo[6];
      Cr[2]=(float)hi[0]; Cz[2]=(float)hi[1]; gn4[2]=(float)hi[2];
      Cr[3]=(float)hi[4]; Cz[3]=(float)hi[5]; gn4[3]=(float)hi[6];

      const f4 aR = __builtin_amdgcn_mfma_f32_16x16x16f16(Ar, bf, Cr, 0, 0, 0);
      const f4 aZ = __builtin_amdgcn_mfma_f32_16x16x16f16(Az, bf, Cz, 0, 0, 0);
      const f4 hN = __builtin_amdgcn_mfma_f32_16x16x16f16(An, bf, Cn, 0, 0, 0);

#pragma unroll
      for (int reg = 0; reg < 4; reg++){
        const float an = fmaf(Wnd[reg], dtv, gn4[reg]);       // 2l2e*(xn part)
        const float r  = frcp(1.f + fexp2(aR[reg]));          // sigmoid
        const float z  = frcp(1.f + fexp2(aZ[reg]));          // sigmoid
        const float ec = fexp2(fmaf(r, hN[reg], an));         // e^{2*pre_n}
        const float n  = fmaf(-2.f, frcp(1.f + ec), 1.f);     // tanh
        hm[reg] = fmaf(z, hm[reg] - n, n);                    // (1-z)*n + z*h
      }
    }
#pragma unroll
    for (int k2 = 0; k2 < 4; k2++){ ic[k2] = icn[k2]; tc[k2] = tcn[k2]; }
  }

  // score: partial dot per lane, reduce across the 4 row-blocks (lanes +-16/32)
  float dot = 0.f;
#pragma unroll
  for (int reg = 0; reg < 4; reg++) dot = fmaf(fcw[reg], hm[reg], dot);
  dot += __shfl_xor(dot, 16);
  dot += __shfl_xor(dot, 32);
  if (q == 0) atomicAdd(out + b, wt * dot);
}

__global__ __launch_bounds__(64) void gru_fused(
    const int* __restrict__ dp,  const float* __restrict__ dp_t,
    const int* __restrict__ cp,  const float* __restrict__ cp_t,
    const h4* __restrict__ Gdp,  const h4* __restrict__ Gcp,
    const float* __restrict__ Wih_dpf, const float* __restrict__ Whh_dpf, const float* __restrict__ bhh_dpf,
    const float* __restrict__ Wih_dpb, const float* __restrict__ Whh_dpb, const float* __restrict__ bhh_dpb,
    const float* __restrict__ Wih_cpf, const float* __restrict__ Whh_cpf, const float* __restrict__ bhh_cpf,
    const float* __restrict__ Wih_cpb, const float* __restrict__ Whh_cpb, const float* __restrict__ bhh_cpb,
    const float* __restrict__ fc_dp_w, const float* __restrict__ fc_cp_w, const float* __restrict__ fc_all_w,
    float* __restrict__ out)
{
  const int wid = blockIdx.x;
  if (wid < 512){
    const int dir = wid >> 8;                   // 0: fwd, 1: bwd
    gru_mfma<9, 4096>(wid & 255, dir, dp, dp_t, Gdp,
        dir ? Wih_dpb : Wih_dpf, dir ? Whh_dpb : Whh_dpf, dir ? bhh_dpb : bhh_dpf,
        fc_dp_w, fc_all_w[20], out);
  } else {
    const int w2 = wid - 512;
    const int dir = w2 >> 8;
    gru_mfma<11, 10000>(w2 & 255, dir, cp, cp_t, Gcp,
        dir ? Wih_cpb : Wih_cpf, dir ? Whh_cpb : Whh_cpf, dir ? bhh_cpb : bhh_cpf,
        fc_cp_w, fc_all_w[21], out);
  }
}

extern "C" void kernel_launch(void* const* d_in, const int* in_sizes, int n_in,
                              void* d_out, int out_size, void* d_ws, size_t ws_size,
                              hipStream_t stream)
{
  const float* stat   = (const float*)d_in[0];
  const int*   dp     = (const int*)  d_in[1];
  const int*   cp     = (const int*)  d_in[2];
  const float* dp_t   = (const float*)d_in[3];
  const float* cp_t   = (const float*)d_in[4];
  const float* emb_dp = (const float*)d_in[5];
  const float* emb_cp = (const float*)d_in[6];

  const float* Wih_dpf = (const float*)d_in[7];
  const float* Whh_dpf = (const float*)d_in[8];
  const float* bih_dpf = (const float*)d_in[9];
  const float* bhh_dpf = (const float*)d_in[10];
  const float* Wih_dpb = (const float*)d_in[11];
  const float* Whh_dpb = (const float*)d_in[12];
  const float* bih_dpb = (const float*)d_in[13];
  const float* bhh_dpb = (const float*)d_in[14];
  const float* Wih_cpf = (const float*)d_in[15];
  const float* Whh_cpf = (const float*)d_in[16];
  const float* bih_cpf = (const float*)d_in[17];
  const float* bhh_cpf = (const float*)d_in[18];
  const float* Wih_cpb = (const float*)d_in[19];
  const float* Whh_cpb = (const float*)d_in[20];
  const float* bih_cpb = (const float*)d_in[21];
  const float* bhh_cpb = (const float*)d_in[22];

  const float* fc_dp_w  = (const float*)d_in[23];
  const float* fc_dp_b  = (const float*)d_in[24];
  const float* fc_cp_w  = (const float*)d_in[25];
  const float* fc_cp_b  = (const float*)d_in[26];
  const float* fc_all_w = (const float*)d_in[27];
  const float* fc_all_b = (const float*)d_in[28];

  float* out = (float*)d_out;

  // workspace: dp table 2*4096*16*8B = 1.00 MB, cp table 2*10000*16*8B = 2.56 MB
  h4* Gdp = (h4*)d_ws;
  h4* Gcp = (h4*)((char*)d_ws + (size_t)(2*4096*16) * sizeof(h4));

  {
    const int total = 2*4096*16 + 2*10000*16 + 4096;
    const int blocks = (total + 255) / 256;
    pre_kernel<<<blocks, 256, 0, stream>>>(
        emb_dp, emb_cp,
        Wih_dpf, bih_dpf, bhh_dpf, Wih_dpb, bih_dpb, bhh_dpb,
        Wih_cpf, bih_cpf, bhh_cpf, Wih_cpb, bih_cpb, bhh_cpb,
        stat, fc_all_w, fc_all_b, fc_dp_b, fc_cp_b,
        Gdp, Gcp, out);
  }

  // 1024 one-wave blocks: 512 dp (fwd+bwd), 512 cp (fwd+bwd), 16 seqs each
  gru_fused<<<1024, 64, 0, stream>>>(
      dp, dp_t, cp, cp_t, Gdp, Gcp,
      Wih_dpf, Whh_dpf, bhh_dpf, Wih_dpb, Whh_dpb, bhh_dpb,
      Wih_cpf, Whh_cpf, bhh_cpf, Wih_cpb, Whh_cpb, bhh_cpb,
      fc_dp_w, fc_cp_w, fc_all_w, out);
}